// Round 4
// baseline (96.384 us; speedup 1.0000x reference)
//
#include <hip/hip_runtime.h>
#include <hip/hip_bf16.h>

// GraphConv: out[t] = sum_{e: tidx[e]==t} input[sidx[e]] * (esgn[e]*enorm[e])
// N_NODES=100000, N_FEAT=128, N_EDGES=600000, fp32.
//
// Round 4: gather_nodes still latency-bound (71us, 35% HBM, 19% VALU).
// The loop carried a bin-load -> row-load dependent chain. Fix:
//  - Lane-parallel bin prefetch: lane l loads bins[node*CAP + (l&31)] once
//    (all 32 bins in one load latency), then __shfl broadcasts src/w.
//  - Row-gather loop unrolled x8 with clamped indices -> up to 8 row loads
//    in flight; mean degree 6 -> one iteration, fully overlapped.

#define CAP 32

struct __align__(8) Bin { int src; float w; };
struct Ovf { int t; int src; float w; };

__global__ void scatter_bins(const int* __restrict__ sidx,
                             const int* __restrict__ tidx,
                             const float* __restrict__ enorm,
                             const float* __restrict__ esgn,
                             Bin* __restrict__ bins,
                             int* __restrict__ counts,
                             Ovf* __restrict__ ovf,
                             int* __restrict__ ovf_count,
                             int ovf_cap,
                             int n_edges) {
    const int e = blockIdx.x * blockDim.x + threadIdx.x;
    if (e >= n_edges) return;
    const int   t = tidx[e];
    const float w = esgn[e] * enorm[e];
    const int slot = atomicAdd(&counts[t], 1);
    if (slot < CAP) {
        Bin b; b.src = sidx[e]; b.w = w;
        bins[(size_t)t * CAP + slot] = b;
    } else {
        const int o = atomicAdd(ovf_count, 1);
        if (o < ovf_cap) { Ovf v; v.t = t; v.src = sidx[e]; v.w = w; ovf[o] = v; }
    }
}

__global__ void gather_nodes(const float* __restrict__ input,
                             const Bin* __restrict__ bins,
                             const int* __restrict__ counts,
                             float* __restrict__ out,
                             int n_nodes) {
    const int node = (blockIdx.x * blockDim.x + threadIdx.x) >> 6;
    const int lane = threadIdx.x & 63;
    if (node >= n_nodes) return;

    const int cnt = min(counts[node], CAP);
    const int off = lane * 2;

    // Lane-parallel bin prefetch: one load latency for all <=32 bins.
    // Lanes 32..63 duplicate lanes 0..31 (same address -> broadcastable).
    const Bin myb = bins[(size_t)node * CAP + (lane & 31)];
    const int   my_src = myb.src;
    const float my_w   = myb.w;

    float2 acc0 = make_float2(0.f, 0.f);
    float2 acc1 = make_float2(0.f, 0.f);

    for (int j = 0; j < cnt; j += 8) {
        int   s[8];
        float w[8];
        #pragma unroll
        for (int k = 0; k < 8; ++k) {
            const int jk = min(j + k, cnt - 1);
            s[k] = __shfl(my_src, jk);
            w[k] = (j + k < cnt) ? __shfl(my_w, jk) : 0.f;
        }
        float2 v[8];
        #pragma unroll
        for (int k = 0; k < 8; ++k)
            v[k] = *reinterpret_cast<const float2*>(input + (size_t)(s[k] * 128 + off));
        #pragma unroll
        for (int k = 0; k < 8; k += 2) {
            acc0.x += v[k].x * w[k];     acc0.y += v[k].y * w[k];
            acc1.x += v[k+1].x * w[k+1]; acc1.y += v[k+1].y * w[k+1];
        }
    }

    float2 r;
    r.x = acc0.x + acc1.x;
    r.y = acc0.y + acc1.y;
    *reinterpret_cast<float2*>(out + (size_t)(node * 128 + off)) = r;  // plain store
}

__global__ void fixup_ovf(const float* __restrict__ input,
                          const Ovf* __restrict__ ovf,
                          const int* __restrict__ ovf_count,
                          float* __restrict__ out,
                          int ovf_cap) {
    const int n = min(*ovf_count, ovf_cap);
    const int wave   = (blockIdx.x * blockDim.x + threadIdx.x) >> 6;
    const int lane   = threadIdx.x & 63;
    const int nwaves = (gridDim.x * blockDim.x) >> 6;
    for (int i = wave; i < n; i += nwaves) {
        const Ovf o = ovf[i];
        const float2 v = *reinterpret_cast<const float2*>(input + (size_t)(o.src * 128 + lane * 2));
        float* dst = out + (size_t)(o.t * 128 + lane * 2);
        atomicAdd(dst + 0, v.x * o.w);
        atomicAdd(dst + 1, v.y * o.w);
    }
}

// Round-1 fallback (atomic scatter) in case ws is too small.
__global__ void graphconv_scatter(const float* __restrict__ input,
                                  const int* __restrict__ sidx,
                                  const int* __restrict__ tidx,
                                  const float* __restrict__ enorm,
                                  const float* __restrict__ esgn,
                                  float* __restrict__ out,
                                  int n_edges) {
    const int gtid   = blockIdx.x * blockDim.x + threadIdx.x;
    const int wave   = gtid >> 6;
    const int lane   = threadIdx.x & 63;
    const int nwaves = (gridDim.x * blockDim.x) >> 6;
    for (int e = wave; e < n_edges; e += nwaves) {
        const float w = esgn[e] * enorm[e];
        const float2 v = *reinterpret_cast<const float2*>(input + (size_t)(sidx[e] * 128 + lane * 2));
        float* dst = out + (size_t)(tidx[e] * 128 + lane * 2);
        atomicAdd(dst + 0, v.x * w);
        atomicAdd(dst + 1, v.y * w);
    }
}

extern "C" void kernel_launch(void* const* d_in, const int* in_sizes, int n_in,
                              void* d_out, int out_size, void* d_ws, size_t ws_size,
                              hipStream_t stream) {
    const float* input = (const float*)d_in[0];
    const int*   sidx  = (const int*)d_in[1];
    const int*   tidx  = (const int*)d_in[2];
    const float* enorm = (const float*)d_in[3];
    const float* esgn  = (const float*)d_in[4];
    float*       out   = (float*)d_out;

    const int n_edges = in_sizes[1];
    const int n_nodes = in_sizes[0] / 128;

    // ws layout: [counts n_nodes ints][ovf_count 1 int][pad->256][bins][ovf...]
    const size_t zero_bytes = ((size_t)n_nodes + 1) * sizeof(int);
    const size_t bins_off   = (zero_bytes + 255) & ~(size_t)255;
    const size_t bins_bytes = (size_t)n_nodes * CAP * sizeof(Bin);
    const size_t ovf_off    = bins_off + bins_bytes;
    const size_t min_ovf    = 4096 * sizeof(Ovf);

    if (ws_size < ovf_off + min_ovf) {
        hipMemsetAsync(d_out, 0, (size_t)out_size * sizeof(float), stream);
        int grid = (n_edges * 64 + 255) / 256;
        if (grid > 2048) grid = 2048;
        graphconv_scatter<<<grid, 256, 0, stream>>>(input, sidx, tidx, enorm, esgn,
                                                    out, n_edges);
        return;
    }

    int* counts    = (int*)d_ws;
    int* ovf_count = (int*)((char*)d_ws + (size_t)n_nodes * sizeof(int));
    Bin* bins      = (Bin*)((char*)d_ws + bins_off);
    Ovf* ovf       = (Ovf*)((char*)d_ws + ovf_off);
    int  ovf_cap   = (int)((ws_size - ovf_off) / sizeof(Ovf));
    if (ovf_cap > n_edges) ovf_cap = n_edges;

    hipMemsetAsync(counts, 0, zero_bytes, stream);   // counters only (no out memset)

    const int block = 256;
    scatter_bins<<<(n_edges + block - 1) / block, block, 0, stream>>>(
        sidx, tidx, enorm, esgn, bins, counts, ovf, ovf_count, ovf_cap, n_edges);

    gather_nodes<<<(int)(((size_t)n_nodes * 64 + block - 1) / block), block, 0, stream>>>(
        input, bins, counts, out, n_nodes);

    fixup_ovf<<<32, block, 0, stream>>>(input, ovf, ovf_count, out, ovf_cap);
}